// Round 6
// baseline (3191.806 us; speedup 1.0000x reference)
//
#include <hip/hip_runtime.h>

// Problem constants (from reference)
#define B_  16
#define T_  2048
#define IN_ 512
#define H_  512
#define M_  (B_ * T_)

// GEMM tiling
#define BM 128
#define BN 128
#define BK 16
#define LDT (BM + 4)     // pad: staging stores 2-way (free), compute reads conflict-free

static __device__ __forceinline__ float4 ld4(const float* p) {
    return *reinterpret_cast<const float4*>(p);
}

// ---------------------------------------------------------------------------
// Kernel 1: h[m][n] = sum_k x[m][k]*W[n][k] + b[n], fp32 VALU.
// k accumulated strictly in order 0..511 with fmaf -> bit-matches np ref
// (absmax 0.0 in R2-R5). DO NOT reorder the k loop.
// LDS ping-pong double buffer (unrolled x2 for static offsets): ONE barrier
// per k-tile; global prefetch loads pinned before compute via a compiler
// memory barrier, consumed into the idle LDS buffer at compute end -> the
// vmcnt drain overlaps ~1 full compute phase instead of stalling the iter top.
// ---------------------------------------------------------------------------

__device__ __forceinline__
void stage_to_lds(float (*__restrict__ Asb)[LDT], float (*__restrict__ Bsb)[LDT],
                  const float4& ra0, const float4& ra1,
                  const float4& rb0, const float4& rb1, int row, int kph) {
    Asb[kph + 0][row]      = ra0.x;  Asb[kph + 1][row]      = ra0.y;
    Asb[kph + 2][row]      = ra0.z;  Asb[kph + 3][row]      = ra0.w;
    Asb[kph + 0][row + 64] = ra1.x;  Asb[kph + 1][row + 64] = ra1.y;
    Asb[kph + 2][row + 64] = ra1.z;  Asb[kph + 3][row + 64] = ra1.w;
    Bsb[kph + 0][row]      = rb0.x;  Bsb[kph + 1][row]      = rb0.y;
    Bsb[kph + 2][row]      = rb0.z;  Bsb[kph + 3][row]      = rb0.w;
    Bsb[kph + 0][row + 64] = rb1.x;  Bsb[kph + 1][row + 64] = rb1.y;
    Bsb[kph + 2][row + 64] = rb1.z;  Bsb[kph + 3][row + 64] = rb1.w;
}

__device__ __forceinline__
void compute_tile(const float (*__restrict__ Asb)[LDT],
                  const float (*__restrict__ Bsb)[LDT],
                  float acc[8][8], int tx, int ty) {
#pragma unroll
    for (int k = 0; k < BK; ++k) {
        float4 av0 = ld4(&Asb[k][ty * 4]);
        float4 av1 = ld4(&Asb[k][ty * 4 + 64]);
        float4 bv0 = ld4(&Bsb[k][tx * 4]);
        float4 bv1 = ld4(&Bsb[k][tx * 4 + 64]);
        const float am[8] = {av0.x, av0.y, av0.z, av0.w,
                             av1.x, av1.y, av1.z, av1.w};
        const float bn8[8] = {bv0.x, bv0.y, bv0.z, bv0.w,
                              bv1.x, bv1.y, bv1.z, bv1.w};
#pragma unroll
        for (int i = 0; i < 8; ++i)
#pragma unroll
            for (int j = 0; j < 8; ++j)
                acc[i][j] = fmaf(am[i], bn8[j], acc[i][j]);
    }
}

__global__ __launch_bounds__(256, 4)
void gemm_xwT(const float* __restrict__ X, const float* __restrict__ W,
              const float* __restrict__ bias, float* __restrict__ Hout) {
    __shared__ float As0[BK][LDT], Bs0[BK][LDT];
    __shared__ float As1[BK][LDT], Bs1[BK][LDT];

    const int tid = threadIdx.x;
    const int m0  = blockIdx.x * BM;   // 256 m-tiles
    const int n0  = blockIdx.y * BN;   // 4 n-tiles

    const int tx = tid & 15;           // col group
    const int ty = tid >> 4;           // row group

    const int row = tid >> 2;          // 0..63
    const int kph = (tid & 3) * 4;     // 0,4,8,12

    const float* pa0 = X + (size_t)(m0 + row) * IN_ + kph;
    const float* pa1 = pa0 + (size_t)64 * IN_;
    const float* pb0 = W + (size_t)(n0 + row) * IN_ + kph;
    const float* pb1 = pb0 + (size_t)64 * IN_;

    float acc[8][8];
#pragma unroll
    for (int i = 0; i < 8; ++i)
#pragma unroll
        for (int j = 0; j < 8; ++j) acc[i][j] = 0.0f;

    // prologue: tile 0 -> buf0
    float4 ra0 = ld4(pa0), ra1 = ld4(pa1), rb0 = ld4(pb0), rb1 = ld4(pb1);
    stage_to_lds(As0, Bs0, ra0, ra1, rb0, rb1, row, kph);
    __syncthreads();

    for (int k0 = 0; k0 < IN_; k0 += 2 * BK) {
        // -------- phase A: compute tile k0 from buf0, stage k0+16 -> buf1 ----
        {
            const int kn = k0 + BK;           // always < 512 here (k0 <= 480)
            ra0 = ld4(pa0 + kn);  ra1 = ld4(pa1 + kn);
            rb0 = ld4(pb0 + kn);  rb1 = ld4(pb1 + kn);
            asm volatile("" ::: "memory");    // pin load issue before compute
            compute_tile(As0, Bs0, acc, tx, ty);
            stage_to_lds(As1, Bs1, ra0, ra1, rb0, rb1, row, kph);
            __syncthreads();
        }
        // -------- phase B: compute tile k0+16 from buf1, stage k0+32 -> buf0 -
        {
            const int kn = k0 + 2 * BK;
            if (kn < IN_) {
                ra0 = ld4(pa0 + kn);  ra1 = ld4(pa1 + kn);
                rb0 = ld4(pb0 + kn);  rb1 = ld4(pb1 + kn);
            }
            asm volatile("" ::: "memory");
            compute_tile(As1, Bs1, acc, tx, ty);
            if (kn < IN_) {
                stage_to_lds(As0, Bs0, ra0, ra1, rb0, rb1, row, kph);
                __syncthreads();
            }
        }
    }

    // epilogue: + bias (bias is zeros -> exact), coalesced float4 stores
    float4 bb0 = ld4(&bias[n0 + tx * 4]);
    float4 bb1 = ld4(&bias[n0 + tx * 4 + 64]);
#pragma unroll
    for (int i = 0; i < 8; ++i) {
        const int r = m0 + ((i < 4) ? (ty * 4 + i) : (64 + ty * 4 + (i - 4)));
        float4 o0, o1;
        o0.x = acc[i][0] + bb0.x;  o0.y = acc[i][1] + bb0.y;
        o0.z = acc[i][2] + bb0.z;  o0.w = acc[i][3] + bb0.w;
        o1.x = acc[i][4] + bb1.x;  o1.y = acc[i][5] + bb1.y;
        o1.z = acc[i][6] + bb1.z;  o1.w = acc[i][7] + bb1.w;
        *reinterpret_cast<float4*>(&Hout[(size_t)r * H_ + n0 + tx * 4])      = o0;
        *reinterpret_cast<float4*>(&Hout[(size_t)r * H_ + n0 + tx * 4 + 64]) = o1;
    }
}

// ---------------------------------------------------------------------------
// Kernel 2: GIF neuron scan. One thread per (b,h) chain; T=2048 steps.
// Wall time = 2048 x dependent-chain period; levers: shorter chain + zero
// slop. Changes vs R5: ping-pong register buffers (no copy loop), loads
// pinned at block top (compiler memory barrier), clamp pairs as v_med3_f32
// (identical result to fmin(fmax(..)) for NaN-free, lo<=hi operands).
// Update expressions and the correctly-rounded div block are VERBATIM from
// the bit-matching R5 kernel. 64-thread blocks spread over 128 CUs.
// ---------------------------------------------------------------------------
#define SPF 32

__device__ __forceinline__
void scan_steps(const float* __restrict__ buf, float* __restrict__ sp,
                int tb, float& v, float& theta) {
    const float DECAY_F = 0.9048374180359595f;  // exp(-1/10)
    const float ALPHA_F = 0.01f;
#pragma unroll
    for (int j = 0; j < SPF; ++j) {
        float cur = buf[j];
        v = v * DECAY_F + cur;
        float cl = 32.0f * theta;                  // L * theta * 2
        v = __builtin_amdgcn_fmed3f(v, -cl, cl);   // == fminf(fmaxf(v,-cl),cl)

        // ---- correctly-rounded v/theta (bit-identical to IEEE div) ----
        float r0 = __builtin_amdgcn_rcpf(theta);   // ~1 ulp
        float e0 = fmaf(-theta, r0, 1.0f);
        float r1 = fmaf(r0, e0, r0);               // N-R 1
        float e1 = fmaf(-theta, r1, 1.0f);
        float r2 = fmaf(r1, e1, r1);               // N-R 2: ~0.5 ulp recip
        float q0 = v * r2;
        float er = fmaf(-theta, q0, v);            // exact residual
        float q  = fmaf(er, r2, q0);               // Markstein: correctly rounded
        // ---------------------------------------------------------------

        float s = floorf(q);
        s = __builtin_amdgcn_fmed3f(s, 0.0f, 16.0f); // == fminf(fmaxf(s,0),16)
        v = v - s * theta;
        theta = theta + ALPHA_F * s - ALPHA_F * (theta - 1.0f);
        sp[(size_t)(tb + j) * H_] = s;
    }
}

__global__ __launch_bounds__(64)
void gif_scan(const float* __restrict__ Hbuf, float* __restrict__ spikes,
              float* __restrict__ vout, float* __restrict__ thout) {
    const int gid = blockIdx.x * 64 + threadIdx.x;    // 0..8191
    const int b = gid >> 9;
    const int h = gid & 511;

    const float* ip = Hbuf   + (size_t)b * T_ * H_ + h;
    float*       sp = spikes + (size_t)b * T_ * H_ + h;

    float bufA[SPF], bufB[SPF];
#pragma unroll
    for (int j = 0; j < SPF; ++j) bufA[j] = ip[(size_t)j * H_];

    float v = 0.0f, theta = 1.0f;
    for (int t0 = 0; t0 < T_; t0 += 2 * SPF) {        // 32 iters, no tail
        // prefetch next block into B, compute from A
#pragma unroll
        for (int j = 0; j < SPF; ++j) bufB[j] = ip[(size_t)(t0 + SPF + j) * H_];
        asm volatile("" ::: "memory");
        scan_steps(bufA, sp, t0, v, theta);

        // prefetch block after next into A, compute from B
        if (t0 + 2 * SPF < T_) {
#pragma unroll
            for (int j = 0; j < SPF; ++j)
                bufA[j] = ip[(size_t)(t0 + 2 * SPF + j) * H_];
        }
        asm volatile("" ::: "memory");
        scan_steps(bufB, sp, t0 + SPF, v, theta);
    }
    vout[gid]  = v;
    thout[gid] = theta;
}

// ---------------------------------------------------------------------------
extern "C" void kernel_launch(void* const* d_in, const int* in_sizes, int n_in,
                              void* d_out, int out_size, void* d_ws, size_t ws_size,
                              hipStream_t stream) {
    const float* x    = (const float*)d_in[0];   // [16, 2048, 512]
    const float* W    = (const float*)d_in[1];   // [512, 512]
    const float* bias = (const float*)d_in[2];   // [512]

    float* out    = (float*)d_out;
    float* spikes = out;
    float* v_f    = out + (size_t)M_ * H_;
    float* th_f   = v_f + (size_t)B_ * H_;

    float* hbuf   = (float*)d_ws;                // 64 MiB scratch for h

    dim3 grid(M_ / BM, H_ / BN);                 // 256 x 4
    gemm_xwT<<<grid, 256, 0, stream>>>(x, W, bias, hbuf);
    gif_scan<<<(B_ * H_) / 64, 64, 0, stream>>>(hbuf, spikes, v_f, th_f);
}

// Round 7
// 437.054 us; speedup vs baseline: 7.3030x; 7.3030x over previous
//
#include <hip/hip_runtime.h>

// Problem constants (from reference)
#define B_  16
#define T_  2048
#define IN_ 512
#define H_  512
#define M_  (B_ * T_)

// GEMM tiling
#define BM 128
#define BN 128
#define BK 16
#define LDT (BM + 4)     // pad: staging stores 2-way (free), compute reads conflict-free

static __device__ __forceinline__ float4 ld4(const float* p) {
    return *reinterpret_cast<const float4*>(p);
}

// ---------------------------------------------------------------------------
// Kernel 1: h[m][n] = sum_k x[m][k]*W[n][k] + b[n], fp32 VALU.
// k accumulated strictly in order 0..511 with fmaf -> bit-matches np ref
// (absmax 0.0 in R2-R6). DO NOT reorder the k loop.
// LDS ping-pong double buffer (unrolled x2 for static offsets): ONE barrier
// per k-tile; global prefetch loads pinned before compute via a compiler
// memory barrier, consumed into the idle LDS buffer at compute end.
// NOTE: plain __launch_bounds__(256). R6's (256,4) forced a 64-VGPR fit and
// spilled acc[8][8] to scratch: FETCH 122MB->3.8GB, 212->3048us. NEVER set
// the min-waves arg on this kernel.
// ---------------------------------------------------------------------------

__device__ __forceinline__
void stage_to_lds(float (*__restrict__ Asb)[LDT], float (*__restrict__ Bsb)[LDT],
                  const float4& ra0, const float4& ra1,
                  const float4& rb0, const float4& rb1, int row, int kph) {
    Asb[kph + 0][row]      = ra0.x;  Asb[kph + 1][row]      = ra0.y;
    Asb[kph + 2][row]      = ra0.z;  Asb[kph + 3][row]      = ra0.w;
    Asb[kph + 0][row + 64] = ra1.x;  Asb[kph + 1][row + 64] = ra1.y;
    Asb[kph + 2][row + 64] = ra1.z;  Asb[kph + 3][row + 64] = ra1.w;
    Bsb[kph + 0][row]      = rb0.x;  Bsb[kph + 1][row]      = rb0.y;
    Bsb[kph + 2][row]      = rb0.z;  Bsb[kph + 3][row]      = rb0.w;
    Bsb[kph + 0][row + 64] = rb1.x;  Bsb[kph + 1][row + 64] = rb1.y;
    Bsb[kph + 2][row + 64] = rb1.z;  Bsb[kph + 3][row + 64] = rb1.w;
}

__device__ __forceinline__
void compute_tile(const float (*__restrict__ Asb)[LDT],
                  const float (*__restrict__ Bsb)[LDT],
                  float acc[8][8], int tx, int ty) {
#pragma unroll
    for (int k = 0; k < BK; ++k) {
        float4 av0 = ld4(&Asb[k][ty * 4]);
        float4 av1 = ld4(&Asb[k][ty * 4 + 64]);
        float4 bv0 = ld4(&Bsb[k][tx * 4]);
        float4 bv1 = ld4(&Bsb[k][tx * 4 + 64]);
        const float am[8] = {av0.x, av0.y, av0.z, av0.w,
                             av1.x, av1.y, av1.z, av1.w};
        const float bn8[8] = {bv0.x, bv0.y, bv0.z, bv0.w,
                              bv1.x, bv1.y, bv1.z, bv1.w};
#pragma unroll
        for (int i = 0; i < 8; ++i)
#pragma unroll
            for (int j = 0; j < 8; ++j)
                acc[i][j] = fmaf(am[i], bn8[j], acc[i][j]);
    }
}

__global__ __launch_bounds__(256)
void gemm_xwT(const float* __restrict__ X, const float* __restrict__ W,
              const float* __restrict__ bias, float* __restrict__ Hout) {
    __shared__ float As0[BK][LDT], Bs0[BK][LDT];
    __shared__ float As1[BK][LDT], Bs1[BK][LDT];

    const int tid = threadIdx.x;
    const int m0  = blockIdx.x * BM;   // 256 m-tiles
    const int n0  = blockIdx.y * BN;   // 4 n-tiles

    const int tx = tid & 15;           // col group
    const int ty = tid >> 4;           // row group

    const int row = tid >> 2;          // 0..63
    const int kph = (tid & 3) * 4;     // 0,4,8,12

    const float* pa0 = X + (size_t)(m0 + row) * IN_ + kph;
    const float* pa1 = pa0 + (size_t)64 * IN_;
    const float* pb0 = W + (size_t)(n0 + row) * IN_ + kph;
    const float* pb1 = pb0 + (size_t)64 * IN_;

    float acc[8][8];
#pragma unroll
    for (int i = 0; i < 8; ++i)
#pragma unroll
        for (int j = 0; j < 8; ++j) acc[i][j] = 0.0f;

    // prologue: tile 0 -> buf0
    float4 ra0 = ld4(pa0), ra1 = ld4(pa1), rb0 = ld4(pb0), rb1 = ld4(pb1);
    stage_to_lds(As0, Bs0, ra0, ra1, rb0, rb1, row, kph);
    __syncthreads();

    for (int k0 = 0; k0 < IN_; k0 += 2 * BK) {
        // -------- phase A: compute tile k0 from buf0, stage k0+16 -> buf1 ----
        {
            const int kn = k0 + BK;           // always < 512 here (k0 <= 480)
            ra0 = ld4(pa0 + kn);  ra1 = ld4(pa1 + kn);
            rb0 = ld4(pb0 + kn);  rb1 = ld4(pb1 + kn);
            asm volatile("" ::: "memory");    // pin load issue before compute
            compute_tile(As0, Bs0, acc, tx, ty);
            stage_to_lds(As1, Bs1, ra0, ra1, rb0, rb1, row, kph);
            __syncthreads();
        }
        // -------- phase B: compute tile k0+16 from buf1, stage k0+32 -> buf0 -
        {
            const int kn = k0 + 2 * BK;
            if (kn < IN_) {
                ra0 = ld4(pa0 + kn);  ra1 = ld4(pa1 + kn);
                rb0 = ld4(pb0 + kn);  rb1 = ld4(pb1 + kn);
            }
            asm volatile("" ::: "memory");
            compute_tile(As1, Bs1, acc, tx, ty);
            if (kn < IN_) {
                stage_to_lds(As0, Bs0, ra0, ra1, rb0, rb1, row, kph);
                __syncthreads();
            }
        }
    }

    // epilogue: + bias (bias is zeros -> exact), coalesced float4 stores
    float4 bb0 = ld4(&bias[n0 + tx * 4]);
    float4 bb1 = ld4(&bias[n0 + tx * 4 + 64]);
#pragma unroll
    for (int i = 0; i < 8; ++i) {
        const int r = m0 + ((i < 4) ? (ty * 4 + i) : (64 + ty * 4 + (i - 4)));
        float4 o0, o1;
        o0.x = acc[i][0] + bb0.x;  o0.y = acc[i][1] + bb0.y;
        o0.z = acc[i][2] + bb0.z;  o0.w = acc[i][3] + bb0.w;
        o1.x = acc[i][4] + bb1.x;  o1.y = acc[i][5] + bb1.y;
        o1.z = acc[i][6] + bb1.z;  o1.w = acc[i][7] + bb1.w;
        *reinterpret_cast<float4*>(&Hout[(size_t)r * H_ + n0 + tx * 4])      = o0;
        *reinterpret_cast<float4*>(&Hout[(size_t)r * H_ + n0 + tx * 4 + 64]) = o1;
    }
}

// ---------------------------------------------------------------------------
// Kernel 2: GIF neuron scan — UNCHANGED from R6 (196 -> ~143us win: med3
// clamps, ping-pong register buffers, 64-thread blocks). One thread per
// (b,h) chain; wall time = 2048 x dependent-chain period (~167 cyc).
// Update expressions + correctly-rounded div block bit-match the np ref
// (absmax 0.0). DO NOT touch the arithmetic statements.
// ---------------------------------------------------------------------------
#define SPF 32

__device__ __forceinline__
void scan_steps(const float* __restrict__ buf, float* __restrict__ sp,
                int tb, float& v, float& theta) {
    const float DECAY_F = 0.9048374180359595f;  // exp(-1/10)
    const float ALPHA_F = 0.01f;
#pragma unroll
    for (int j = 0; j < SPF; ++j) {
        float cur = buf[j];
        v = v * DECAY_F + cur;
        float cl = 32.0f * theta;                  // L * theta * 2
        v = __builtin_amdgcn_fmed3f(v, -cl, cl);   // == fminf(fmaxf(v,-cl),cl)

        // ---- correctly-rounded v/theta (bit-identical to IEEE div) ----
        float r0 = __builtin_amdgcn_rcpf(theta);   // ~1 ulp
        float e0 = fmaf(-theta, r0, 1.0f);
        float r1 = fmaf(r0, e0, r0);               // N-R 1
        float e1 = fmaf(-theta, r1, 1.0f);
        float r2 = fmaf(r1, e1, r1);               // N-R 2: ~0.5 ulp recip
        float q0 = v * r2;
        float er = fmaf(-theta, q0, v);            // exact residual
        float q  = fmaf(er, r2, q0);               // Markstein: correctly rounded
        // ---------------------------------------------------------------

        float s = floorf(q);
        s = __builtin_amdgcn_fmed3f(s, 0.0f, 16.0f); // == fminf(fmaxf(s,0),16)
        v = v - s * theta;
        theta = theta + ALPHA_F * s - ALPHA_F * (theta - 1.0f);
        sp[(size_t)(tb + j) * H_] = s;
    }
}

__global__ __launch_bounds__(64)
void gif_scan(const float* __restrict__ Hbuf, float* __restrict__ spikes,
              float* __restrict__ vout, float* __restrict__ thout) {
    const int gid = blockIdx.x * 64 + threadIdx.x;    // 0..8191
    const int b = gid >> 9;
    const int h = gid & 511;

    const float* ip = Hbuf   + (size_t)b * T_ * H_ + h;
    float*       sp = spikes + (size_t)b * T_ * H_ + h;

    float bufA[SPF], bufB[SPF];
#pragma unroll
    for (int j = 0; j < SPF; ++j) bufA[j] = ip[(size_t)j * H_];

    float v = 0.0f, theta = 1.0f;
    for (int t0 = 0; t0 < T_; t0 += 2 * SPF) {        // 32 iters, no tail
        // prefetch next block into B, compute from A
#pragma unroll
        for (int j = 0; j < SPF; ++j) bufB[j] = ip[(size_t)(t0 + SPF + j) * H_];
        asm volatile("" ::: "memory");
        scan_steps(bufA, sp, t0, v, theta);

        // prefetch block after next into A, compute from B
        if (t0 + 2 * SPF < T_) {
#pragma unroll
            for (int j = 0; j < SPF; ++j)
                bufA[j] = ip[(size_t)(t0 + 2 * SPF + j) * H_];
        }
        asm volatile("" ::: "memory");
        scan_steps(bufB, sp, t0 + SPF, v, theta);
    }
    vout[gid]  = v;
    thout[gid] = theta;
}

// ---------------------------------------------------------------------------
extern "C" void kernel_launch(void* const* d_in, const int* in_sizes, int n_in,
                              void* d_out, int out_size, void* d_ws, size_t ws_size,
                              hipStream_t stream) {
    const float* x    = (const float*)d_in[0];   // [16, 2048, 512]
    const float* W    = (const float*)d_in[1];   // [512, 512]
    const float* bias = (const float*)d_in[2];   // [512]

    float* out    = (float*)d_out;
    float* spikes = out;
    float* v_f    = out + (size_t)M_ * H_;
    float* th_f   = v_f + (size_t)B_ * H_;

    float* hbuf   = (float*)d_ws;                // 64 MiB scratch for h

    dim3 grid(M_ / BM, H_ / BN);                 // 256 x 4
    gemm_xwT<<<grid, 256, 0, stream>>>(x, W, bias, hbuf);
    gif_scan<<<(B_ * H_) / 64, 64, 0, stream>>>(hbuf, spikes, v_f, th_f);
}